// Round 1
// baseline (2907.886 us; speedup 1.0000x reference)
//
#include <hip/hip_runtime.h>

#define DD 64
constexpr int N_P   = 100000;
constexpr int N_G   = 40000;
constexpr int NE    = 1600000;
constexpr int E_LBL = 500000;
constexpr int F_GO  = 1000;

// ---------------- gather rows: out[i] = emb[nid[i]] ----------------
__global__ void gather_rows(const float* __restrict__ emb, const int* __restrict__ nid,
                            float* __restrict__ out, int n) {
    int t = blockIdx.x * blockDim.x + threadIdx.x;   // one float4 per thread
    int total = n * (DD / 4);
    if (t >= total) return;
    int row = t / (DD / 4);
    int c4  = t % (DD / 4);
    int srow = nid[row];
    reinterpret_cast<float4*>(out)[(size_t)row * (DD / 4) + c4] =
        reinterpret_cast<const float4*>(emb)[(size_t)srow * (DD / 4) + c4];
}

// ---------------- xg = go_x @ lin_W + lin_b + go_emb[go_nid] ----------------
// M=40000 (div by 64), K=1000, N=64. Block tile 64x64, K-tile 100.
__global__ __launch_bounds__(256) void lin_go(const float* __restrict__ go_x,
        const float* __restrict__ lin_W, const float* __restrict__ lin_b,
        const float* __restrict__ go_emb, const int* __restrict__ go_nid,
        float* __restrict__ out) {
    constexpr int KT = 100;
    __shared__ float As[64][104];    // padded to mult-of-4 for float4 alignment
    __shared__ float Ws[KT][64];
    int tid = threadIdx.x;
    int tx = tid % 16, ty = tid / 16;
    int row0 = blockIdx.x * 64;
    float acc[4][4] = {};
    for (int k0 = 0; k0 < F_GO; k0 += KT) {
        for (int idx = tid; idx < 64 * KT; idx += 256) {
            int rr = idx / KT, kk = idx % KT;
            As[rr][kk] = go_x[(size_t)(row0 + rr) * F_GO + k0 + kk];
        }
        for (int idx = tid; idx < KT * 64; idx += 256) {
            int kk = idx >> 6, j = idx & 63;
            Ws[kk][j] = lin_W[(size_t)(k0 + kk) * 64 + j];
        }
        __syncthreads();
        for (int k = 0; k < KT; k += 4) {
            float a[4][4], w[4][4];
#pragma unroll
            for (int r = 0; r < 4; ++r)
                *reinterpret_cast<float4*>(a[r]) = *reinterpret_cast<const float4*>(&As[ty * 4 + r][k]);
#pragma unroll
            for (int kk = 0; kk < 4; ++kk)
                *reinterpret_cast<float4*>(w[kk]) = *reinterpret_cast<const float4*>(&Ws[k + kk][tx * 4]);
#pragma unroll
            for (int r = 0; r < 4; ++r)
#pragma unroll
                for (int c = 0; c < 4; ++c)
                    acc[r][c] += a[r][0] * w[0][c] + a[r][1] * w[1][c]
                               + a[r][2] * w[2][c] + a[r][3] * w[3][c];
        }
        __syncthreads();
    }
#pragma unroll
    for (int r = 0; r < 4; ++r) {
        int row = row0 + ty * 4 + r;
        int nid = go_nid[row];
#pragma unroll
        for (int c = 0; c < 4; ++c) {
            int j = tx * 4 + c;
            out[(size_t)row * 64 + j] = acc[r][c] + lin_b[j] + go_emb[(size_t)nid * 64 + j];
        }
    }
}

// ---------------- degree histogram ----------------
__global__ void count_edges(const int* __restrict__ dst, float* __restrict__ cnt, int nE) {
    int e = blockIdx.x * blockDim.x + threadIdx.x;
    if (e < nE) atomicAdd(&cnt[dst[e]], 1.0f);
}

// ---------------- scatter-add: sum[dst] += x[src] ----------------
__global__ void scatter_add(const float* __restrict__ x, const int* __restrict__ src,
                            const int* __restrict__ dst, float* __restrict__ sum, int nE) {
    int e = blockIdx.x * 4 + (threadIdx.x >> 6);   // one wave per edge
    int lane = threadIdx.x & 63;
    if (e >= nE) return;
    int s = src[e], d = dst[e];
    atomicAdd(&sum[(size_t)d * 64 + lane], x[(size_t)s * 64 + lane]);
}

// ---------------- node update: out = (sum/cnt)@Wl + bias + x@Wr, optional ReLU ----
// Fused as [n,128] @ [128,64]. out may alias sum (in-place, row-disjoint per block).
__global__ __launch_bounds__(256) void update_nodes(
        const float* sum, const float* __restrict__ cnt, const float* __restrict__ x,
        const float* __restrict__ Wl, const float* __restrict__ bias,
        const float* __restrict__ Wr, float* out, int n, int relu) {
    __shared__ float As[64][132];    // [row][k], k in [0,128) = [agg | x]
    __shared__ float Ws[128][64];    // [k][col] = [Wl ; Wr]
    int tid = threadIdx.x;
    int j = tid & 63, rg = tid >> 6;
    int tx = tid % 16, ty = tid / 16;
    int row0 = blockIdx.x * 64;
    for (int idx = tid; idx < 64 * 64; idx += 256) {
        int k = idx >> 6, c = idx & 63;
        Ws[k][c]      = Wl[idx];
        Ws[64 + k][c] = Wr[idx];
    }
    for (int rr = rg; rr < 64; rr += 4) {
        int row = row0 + rr;
        int rc = min(row, n - 1);
        float inv = 1.0f / fmaxf(cnt[rc], 1.0f);
        As[rr][j]      = sum[(size_t)rc * 64 + j] * inv;
        As[rr][64 + j] = x[(size_t)rc * 64 + j];
    }
    __syncthreads();
    float acc[4][4] = {};
    for (int k = 0; k < 128; k += 4) {
        float a[4][4], w[4][4];
#pragma unroll
        for (int r = 0; r < 4; ++r)
            *reinterpret_cast<float4*>(a[r]) = *reinterpret_cast<const float4*>(&As[ty * 4 + r][k]);
#pragma unroll
        for (int kk = 0; kk < 4; ++kk)
            *reinterpret_cast<float4*>(w[kk]) = *reinterpret_cast<const float4*>(&Ws[k + kk][tx * 4]);
#pragma unroll
        for (int r = 0; r < 4; ++r)
#pragma unroll
            for (int c = 0; c < 4; ++c)
                acc[r][c] += a[r][0] * w[0][c] + a[r][1] * w[1][c]
                           + a[r][2] * w[2][c] + a[r][3] * w[3][c];
    }
#pragma unroll
    for (int r = 0; r < 4; ++r) {
        int row = row0 + ty * 4 + r;
        if (row >= n) continue;
#pragma unroll
        for (int c = 0; c < 4; ++c) {
            int col = tx * 4 + c;
            float v = acc[r][c] + bias[col];
            if (relu) v = fmaxf(v, 0.0f);
            out[(size_t)row * 64 + col] = v;
        }
    }
}

// ---------------- classifier: out[e] = dot(xp[ls[e]], xg[ld[e]]) ----------------
__global__ void classify(const float* __restrict__ xp, const float* __restrict__ xg,
                         const int* __restrict__ ls, const int* __restrict__ ld,
                         float* __restrict__ out, int nE) {
    int e = blockIdx.x * 4 + (threadIdx.x >> 6);   // one wave per edge
    int lane = threadIdx.x & 63;
    if (e >= nE) return;
    int s = ls[e], d = ld[e];
    float v = xp[(size_t)s * 64 + lane] * xg[(size_t)d * 64 + lane];
#pragma unroll
    for (int off = 32; off; off >>= 1) v += __shfl_down(v, off);
    if (lane == 0) out[e] = v;
}

extern "C" void kernel_launch(void* const* d_in, const int* in_sizes, int n_in,
                              void* d_out, int out_size, void* d_ws, size_t ws_size,
                              hipStream_t stream) {
    const float* go_x        = (const float*)d_in[0];
    const float* protein_emb = (const float*)d_in[1];
    const float* go_emb      = (const float*)d_in[2];
    const float* lin_W       = (const float*)d_in[3];
    const float* lin_b       = (const float*)d_in[4];
    const float* Wl          = (const float*)d_in[5];
    const float* bl          = (const float*)d_in[6];
    const float* Wr          = (const float*)d_in[7];
    const int* protein_nid   = (const int*)d_in[8];
    const int* go_nid        = (const int*)d_in[9];
    const int* src_pg        = (const int*)d_in[10];
    const int* dst_pg        = (const int*)d_in[11];
    const int* src_gp        = (const int*)d_in[12];
    const int* dst_gp        = (const int*)d_in[13];
    const int* label_src     = (const int*)d_in[14];
    const int* label_dst     = (const int*)d_in[15];
    float* out = (float*)d_out;

    float* ws = (float*)d_ws;
    float* p0 = ws;
    float* p1 = p0 + (size_t)N_P * 64;
    float* g0 = p1 + (size_t)N_P * 64;
    float* g1 = g0 + (size_t)N_G * 64;
    float* cnt_p = g1 + (size_t)N_G * 64;
    float* cnt_g = cnt_p + N_P;

    hipMemsetAsync(cnt_p, 0, (size_t)(N_P + N_G) * sizeof(float), stream);
    gather_rows<<<(N_P * (DD / 4) + 255) / 256, 256, 0, stream>>>(protein_emb, protein_nid, p0, N_P);
    lin_go<<<N_G / 64, 256, 0, stream>>>(go_x, lin_W, lin_b, go_emb, go_nid, g0);
    count_edges<<<(NE + 255) / 256, 256, 0, stream>>>(dst_pg, cnt_g, NE);
    count_edges<<<(NE + 255) / 256, 256, 0, stream>>>(dst_gp, cnt_p, NE);

    float* xp = p0; float* xg = g0; float* sp = p1; float* sg = g1;
    for (int l = 0; l < 3; ++l) {
        hipMemsetAsync(sp, 0, (size_t)N_P * 64 * sizeof(float), stream);
        hipMemsetAsync(sg, 0, (size_t)N_G * 64 * sizeof(float), stream);
        scatter_add<<<(NE + 3) / 4, 256, 0, stream>>>(xp, src_pg, dst_pg, sg, NE);
        scatter_add<<<(NE + 3) / 4, 256, 0, stream>>>(xg, src_gp, dst_gp, sp, NE);
        int relu = (l < 2) ? 1 : 0;
        const float* wl0 = Wl + (size_t)(l * 2 + 0) * 4096;
        const float* wl1 = Wl + (size_t)(l * 2 + 1) * 4096;
        const float* wr0 = Wr + (size_t)(l * 2 + 0) * 4096;
        const float* wr1 = Wr + (size_t)(l * 2 + 1) * 4096;
        const float* b0  = bl + (size_t)(l * 2 + 0) * 64;
        const float* b1  = bl + (size_t)(l * 2 + 1) * 64;
        update_nodes<<<(N_G + 63) / 64, 256, 0, stream>>>(sg, cnt_g, xg, wl0, b0, wr0, sg, N_G, relu);
        update_nodes<<<(N_P + 63) / 64, 256, 0, stream>>>(sp, cnt_p, xp, wl1, b1, wr1, sp, N_P, relu);
        float* t;
        t = xp; xp = sp; sp = t;
        t = xg; xg = sg; sg = t;
    }
    classify<<<(E_LBL + 3) / 4, 256, 0, stream>>>(xp, xg, label_src, label_dst, out, E_LBL);
}

// Round 2
// 1370.734 us; speedup vs baseline: 2.1214x; 2.1214x over previous
//
#include <hip/hip_runtime.h>

#define DD 64
constexpr int N_P   = 100000;
constexpr int N_G   = 40000;
constexpr int NE    = 1600000;
constexpr int E_LBL = 500000;
constexpr int F_GO  = 1000;

// ---------------- gather rows: out[i] = emb[nid[i]] ----------------
__global__ void gather_rows(const float* __restrict__ emb, const int* __restrict__ nid,
                            float* __restrict__ out, int n) {
    int t = blockIdx.x * blockDim.x + threadIdx.x;   // one float4 per thread
    int total = n * (DD / 4);
    if (t >= total) return;
    int row = t / (DD / 4);
    int c4  = t % (DD / 4);
    int srow = nid[row];
    reinterpret_cast<float4*>(out)[(size_t)row * (DD / 4) + c4] =
        reinterpret_cast<const float4*>(emb)[(size_t)srow * (DD / 4) + c4];
}

// ---------------- xg = go_x @ lin_W + lin_b + go_emb[go_nid] ----------------
__global__ __launch_bounds__(256) void lin_go(const float* __restrict__ go_x,
        const float* __restrict__ lin_W, const float* __restrict__ lin_b,
        const float* __restrict__ go_emb, const int* __restrict__ go_nid,
        float* __restrict__ out) {
    constexpr int KT = 100;
    __shared__ float As[64][104];
    __shared__ float Ws[KT][64];
    int tid = threadIdx.x;
    int tx = tid % 16, ty = tid / 16;
    int row0 = blockIdx.x * 64;
    float acc[4][4] = {};
    for (int k0 = 0; k0 < F_GO; k0 += KT) {
        for (int idx = tid; idx < 64 * KT; idx += 256) {
            int rr = idx / KT, kk = idx % KT;
            As[rr][kk] = go_x[(size_t)(row0 + rr) * F_GO + k0 + kk];
        }
        for (int idx = tid; idx < KT * 64; idx += 256) {
            int kk = idx >> 6, j = idx & 63;
            Ws[kk][j] = lin_W[(size_t)(k0 + kk) * 64 + j];
        }
        __syncthreads();
        for (int k = 0; k < KT; k += 4) {
            float a[4][4], w[4][4];
#pragma unroll
            for (int r = 0; r < 4; ++r)
                *reinterpret_cast<float4*>(a[r]) = *reinterpret_cast<const float4*>(&As[ty * 4 + r][k]);
#pragma unroll
            for (int kk = 0; kk < 4; ++kk)
                *reinterpret_cast<float4*>(w[kk]) = *reinterpret_cast<const float4*>(&Ws[k + kk][tx * 4]);
#pragma unroll
            for (int r = 0; r < 4; ++r)
#pragma unroll
                for (int c = 0; c < 4; ++c)
                    acc[r][c] += a[r][0] * w[0][c] + a[r][1] * w[1][c]
                               + a[r][2] * w[2][c] + a[r][3] * w[3][c];
        }
        __syncthreads();
    }
#pragma unroll
    for (int r = 0; r < 4; ++r) {
        int row = row0 + ty * 4 + r;
        int nid = go_nid[row];
#pragma unroll
        for (int c = 0; c < 4; ++c) {
            int j = tx * 4 + c;
            out[(size_t)row * 64 + j] = acc[r][c] + lin_b[j] + go_emb[(size_t)nid * 64 + j];
        }
    }
}

// ---------------- CSR build ----------------
__global__ void count_int(const int* __restrict__ dst, int* __restrict__ cnt, int nE) {
    int e = blockIdx.x * blockDim.x + threadIdx.x;
    if (e < nE) atomicAdd(&cnt[dst[e]], 1);
}

// exclusive scan within 1024-blocks; emits per-block totals
__global__ __launch_bounds__(1024) void scan_local(const int* __restrict__ cnt,
        int* __restrict__ loc, int* __restrict__ bsum, int n) {
    __shared__ int sh[1024];
    int i = blockIdx.x * 1024 + threadIdx.x;
    int v = (i < n) ? cnt[i] : 0;
    sh[threadIdx.x] = v;
    __syncthreads();
    for (int off = 1; off < 1024; off <<= 1) {
        int t = (threadIdx.x >= off) ? sh[threadIdx.x - off] : 0;
        __syncthreads();
        sh[threadIdx.x] += t;
        __syncthreads();
    }
    if (i < n) loc[i] = sh[threadIdx.x] - v;
    if (threadIdx.x == 1023) bsum[blockIdx.x] = sh[1023];
}

// single-block exclusive scan of block sums (nb <= 1024)
__global__ __launch_bounds__(1024) void scan_bsum(int* __restrict__ bsum, int nb) {
    __shared__ int sh[1024];
    int v = (threadIdx.x < nb) ? bsum[threadIdx.x] : 0;
    sh[threadIdx.x] = v;
    __syncthreads();
    for (int off = 1; off < 1024; off <<= 1) {
        int t = (threadIdx.x >= off) ? sh[threadIdx.x - off] : 0;
        __syncthreads();
        sh[threadIdx.x] += t;
        __syncthreads();
    }
    if (threadIdx.x < nb) bsum[threadIdx.x] = sh[threadIdx.x] - v;
}

__global__ void scan_add(const int* __restrict__ loc, const int* __restrict__ bsum,
                         int* __restrict__ rowptr, int* __restrict__ cursor, int n, int total) {
    int i = blockIdx.x * blockDim.x + threadIdx.x;
    if (i < n) {
        int v = loc[i] + bsum[i >> 10];
        rowptr[i] = v;
        cursor[i] = v;
    }
    if (i == n) rowptr[n] = total;
}

__global__ void fill_csr(const int* __restrict__ src, const int* __restrict__ dst,
                         int* __restrict__ cursor, int* __restrict__ csr_src, int nE) {
    int e = blockIdx.x * blockDim.x + threadIdx.x;
    if (e >= nE) return;
    int slot = atomicAdd(&cursor[dst[e]], 1);
    csr_src[slot] = src[e];
}

// ---------------- aggregation: out[d] = mean over CSR edges of x[src] ----------
__global__ void aggregate_csr(const float* __restrict__ x, const int* __restrict__ rowptr,
                              const int* __restrict__ csr_src, float* __restrict__ out, int n) {
    int row = blockIdx.x * 4 + (threadIdx.x >> 6);   // one wave per dst row
    int lane = threadIdx.x & 63;
    if (row >= n) return;
    int s = rowptr[row], e = rowptr[row + 1];
    float a0 = 0.f, a1 = 0.f, a2 = 0.f, a3 = 0.f;
    int i = s;
    for (; i + 4 <= e; i += 4) {
        int s0 = csr_src[i], s1 = csr_src[i + 1], s2 = csr_src[i + 2], s3 = csr_src[i + 3];
        a0 += x[(size_t)s0 * 64 + lane];
        a1 += x[(size_t)s1 * 64 + lane];
        a2 += x[(size_t)s2 * 64 + lane];
        a3 += x[(size_t)s3 * 64 + lane];
    }
    for (; i < e; ++i) a0 += x[(size_t)csr_src[i] * 64 + lane];
    float inv = (e > s) ? 1.0f / (float)(e - s) : 0.0f;
    out[(size_t)row * 64 + lane] = (a0 + a1 + a2 + a3) * inv;
}

// ---------------- node update: out = agg@Wl + bias + x@Wr, optional ReLU ----
// agg already mean-divided. out may alias agg (in-place, block reads only its own rows).
__global__ __launch_bounds__(256) void update_nodes(
        const float* agg, const float* __restrict__ x,
        const float* __restrict__ Wl, const float* __restrict__ bias,
        const float* __restrict__ Wr, float* out, int n, int relu) {
    __shared__ float As[64][132];    // [row][k], k in [0,128) = [agg | x]
    __shared__ float Ws[128][64];    // [k][col] = [Wl ; Wr]
    int tid = threadIdx.x;
    int j = tid & 63, rg = tid >> 6;
    int tx = tid % 16, ty = tid / 16;
    int row0 = blockIdx.x * 64;
    for (int idx = tid; idx < 64 * 64; idx += 256) {
        int k = idx >> 6, c = idx & 63;
        Ws[k][c]      = Wl[idx];
        Ws[64 + k][c] = Wr[idx];
    }
    for (int rr = rg; rr < 64; rr += 4) {
        int row = row0 + rr;
        int rc = min(row, n - 1);
        As[rr][j]      = agg[(size_t)rc * 64 + j];
        As[rr][64 + j] = x[(size_t)rc * 64 + j];
    }
    __syncthreads();
    float acc[4][4] = {};
    for (int k = 0; k < 128; k += 4) {
        float a[4][4], w[4][4];
#pragma unroll
        for (int r = 0; r < 4; ++r)
            *reinterpret_cast<float4*>(a[r]) = *reinterpret_cast<const float4*>(&As[ty * 4 + r][k]);
#pragma unroll
        for (int kk = 0; kk < 4; ++kk)
            *reinterpret_cast<float4*>(w[kk]) = *reinterpret_cast<const float4*>(&Ws[k + kk][tx * 4]);
#pragma unroll
        for (int r = 0; r < 4; ++r)
#pragma unroll
            for (int c = 0; c < 4; ++c)
                acc[r][c] += a[r][0] * w[0][c] + a[r][1] * w[1][c]
                           + a[r][2] * w[2][c] + a[r][3] * w[3][c];
    }
#pragma unroll
    for (int r = 0; r < 4; ++r) {
        int row = row0 + ty * 4 + r;
        if (row >= n) continue;
#pragma unroll
        for (int c = 0; c < 4; ++c) {
            int col = tx * 4 + c;
            float v = acc[r][c] + bias[col];
            if (relu) v = fmaxf(v, 0.0f);
            out[(size_t)row * 64 + col] = v;
        }
    }
}

// ---------------- classifier: out[e] = dot(xp[ls[e]], xg[ld[e]]) ----------------
__global__ void classify(const float* __restrict__ xp, const float* __restrict__ xg,
                         const int* __restrict__ ls, const int* __restrict__ ld,
                         float* __restrict__ out, int nE) {
    int e = blockIdx.x * 4 + (threadIdx.x >> 6);   // one wave per edge
    int lane = threadIdx.x & 63;
    if (e >= nE) return;
    int s = ls[e], d = ld[e];
    float v = xp[(size_t)s * 64 + lane] * xg[(size_t)d * 64 + lane];
#pragma unroll
    for (int off = 32; off; off >>= 1) v += __shfl_down(v, off);
    if (lane == 0) out[e] = v;
}

extern "C" void kernel_launch(void* const* d_in, const int* in_sizes, int n_in,
                              void* d_out, int out_size, void* d_ws, size_t ws_size,
                              hipStream_t stream) {
    const float* go_x        = (const float*)d_in[0];
    const float* protein_emb = (const float*)d_in[1];
    const float* go_emb      = (const float*)d_in[2];
    const float* lin_W       = (const float*)d_in[3];
    const float* lin_b       = (const float*)d_in[4];
    const float* Wl          = (const float*)d_in[5];
    const float* bl          = (const float*)d_in[6];
    const float* Wr          = (const float*)d_in[7];
    const int* protein_nid   = (const int*)d_in[8];
    const int* go_nid        = (const int*)d_in[9];
    const int* src_pg        = (const int*)d_in[10];
    const int* dst_pg        = (const int*)d_in[11];
    const int* src_gp        = (const int*)d_in[12];
    const int* dst_gp        = (const int*)d_in[13];
    const int* label_src     = (const int*)d_in[14];
    const int* label_dst     = (const int*)d_in[15];
    float* out = (float*)d_out;

    // ---- workspace layout ----
    float* ws = (float*)d_ws;
    float* p0 = ws;
    float* p1 = p0 + (size_t)N_P * 64;
    float* g0 = p1 + (size_t)N_P * 64;
    float* g1 = g0 + (size_t)N_G * 64;
    int* ib = (int*)(g1 + (size_t)N_G * 64);
    int* rowptr_g = ib;                 ib += N_G + 1;
    int* cursor_g = ib;                 ib += N_G + 1;
    int* rowptr_p = ib;                 ib += N_P + 1;
    int* cursor_p = ib;                 ib += N_P + 1;
    int* cnt_i    = ib;                 ib += N_P;        // reused for both sides
    int* loc      = ib;                 ib += N_P;        // reused
    int* bsum     = ib;                 ib += 1024;
    int* csr_g    = ib;                 ib += NE;
    int* csr_p    = ib;                 ib += NE;

    // ---- input embeddings (independent of CSR build) ----
    gather_rows<<<(N_P * (DD / 4) + 255) / 256, 256, 0, stream>>>(protein_emb, protein_nid, p0, N_P);
    lin_go<<<N_G / 64, 256, 0, stream>>>(go_x, lin_W, lin_b, go_emb, go_nid, g0);

    // ---- build CSR for p->g edges (grouped by dst_pg, n=N_G) ----
    hipMemsetAsync(cnt_i, 0, (size_t)N_G * sizeof(int), stream);
    count_int<<<(NE + 255) / 256, 256, 0, stream>>>(dst_pg, cnt_i, NE);
    scan_local<<<(N_G + 1023) / 1024, 1024, 0, stream>>>(cnt_i, loc, bsum, N_G);
    scan_bsum<<<1, 1024, 0, stream>>>(bsum, (N_G + 1023) / 1024);
    scan_add<<<(N_G + 256) / 256, 256, 0, stream>>>(loc, bsum, rowptr_g, cursor_g, N_G, NE);
    fill_csr<<<(NE + 255) / 256, 256, 0, stream>>>(src_pg, dst_pg, cursor_g, csr_g, NE);

    // ---- build CSR for g->p edges (grouped by dst_gp, n=N_P) ----
    hipMemsetAsync(cnt_i, 0, (size_t)N_P * sizeof(int), stream);
    count_int<<<(NE + 255) / 256, 256, 0, stream>>>(dst_gp, cnt_i, NE);
    scan_local<<<(N_P + 1023) / 1024, 1024, 0, stream>>>(cnt_i, loc, bsum, N_P);
    scan_bsum<<<1, 1024, 0, stream>>>(bsum, (N_P + 1023) / 1024);
    scan_add<<<(N_P + 256) / 256, 256, 0, stream>>>(loc, bsum, rowptr_p, cursor_p, N_P, NE);
    fill_csr<<<(NE + 255) / 256, 256, 0, stream>>>(src_gp, dst_gp, cursor_p, csr_p, NE);

    // ---- layers ----
    float* xp = p0; float* xg = g0; float* sp = p1; float* sg = g1;
    for (int l = 0; l < 3; ++l) {
        aggregate_csr<<<(N_G + 3) / 4, 256, 0, stream>>>(xp, rowptr_g, csr_g, sg, N_G);
        aggregate_csr<<<(N_P + 3) / 4, 256, 0, stream>>>(xg, rowptr_p, csr_p, sp, N_P);
        int relu = (l < 2) ? 1 : 0;
        const float* wl0 = Wl + (size_t)(l * 2 + 0) * 4096;
        const float* wl1 = Wl + (size_t)(l * 2 + 1) * 4096;
        const float* wr0 = Wr + (size_t)(l * 2 + 0) * 4096;
        const float* wr1 = Wr + (size_t)(l * 2 + 1) * 4096;
        const float* b0  = bl + (size_t)(l * 2 + 0) * 64;
        const float* b1  = bl + (size_t)(l * 2 + 1) * 64;
        update_nodes<<<(N_G + 63) / 64, 256, 0, stream>>>(sg, xg, wl0, b0, wr0, sg, N_G, relu);
        update_nodes<<<(N_P + 63) / 64, 256, 0, stream>>>(sp, xp, wl1, b1, wr1, sp, N_P, relu);
        float* t;
        t = xp; xp = sp; sp = t;
        t = xg; xg = sg; sg = t;
    }
    classify<<<(E_LBL + 3) / 4, 256, 0, stream>>>(xp, xg, label_src, label_dst, out, E_LBL);
}

// Round 3
// 1264.699 us; speedup vs baseline: 2.2993x; 1.0838x over previous
//
#include <hip/hip_runtime.h>

#define DD 64
constexpr int N_P   = 100000;
constexpr int N_G   = 40000;
constexpr int NE    = 1600000;
constexpr int E_LBL = 500000;
constexpr int F_GO  = 1000;

// ---------------- gather rows: out[i] = emb[nid[i]] ----------------
__global__ void gather_rows(const float* __restrict__ emb, const int* __restrict__ nid,
                            float* __restrict__ out, int n) {
    int t = blockIdx.x * blockDim.x + threadIdx.x;   // one float4 per thread
    int total = n * (DD / 4);
    if (t >= total) return;
    int row = t / (DD / 4);
    int c4  = t % (DD / 4);
    int srow = nid[row];
    reinterpret_cast<float4*>(out)[(size_t)row * (DD / 4) + c4] =
        reinterpret_cast<const float4*>(emb)[(size_t)srow * (DD / 4) + c4];
}

// ---------------- xg = go_x @ lin_W + lin_b + go_emb[go_nid] ----------------
__global__ __launch_bounds__(256) void lin_go(const float* __restrict__ go_x,
        const float* __restrict__ lin_W, const float* __restrict__ lin_b,
        const float* __restrict__ go_emb, const int* __restrict__ go_nid,
        float* __restrict__ out) {
    constexpr int KT = 100;
    __shared__ float As[64][104];
    __shared__ float Ws[KT][64];
    int tid = threadIdx.x;
    int tx = tid % 16, ty = tid / 16;
    int row0 = blockIdx.x * 64;
    float acc[4][4] = {};
    for (int k0 = 0; k0 < F_GO; k0 += KT) {
        for (int idx = tid; idx < 64 * KT; idx += 256) {
            int rr = idx / KT, kk = idx % KT;
            As[rr][kk] = go_x[(size_t)(row0 + rr) * F_GO + k0 + kk];
        }
        for (int idx = tid; idx < KT * 64; idx += 256) {
            int kk = idx >> 6, j = idx & 63;
            Ws[kk][j] = lin_W[(size_t)(k0 + kk) * 64 + j];
        }
        __syncthreads();
        for (int k = 0; k < KT; k += 4) {
            float a[4][4], w[4][4];
#pragma unroll
            for (int r = 0; r < 4; ++r)
                *reinterpret_cast<float4*>(a[r]) = *reinterpret_cast<const float4*>(&As[ty * 4 + r][k]);
#pragma unroll
            for (int kk = 0; kk < 4; ++kk)
                *reinterpret_cast<float4*>(w[kk]) = *reinterpret_cast<const float4*>(&Ws[k + kk][tx * 4]);
#pragma unroll
            for (int r = 0; r < 4; ++r)
#pragma unroll
                for (int c = 0; c < 4; ++c)
                    acc[r][c] += a[r][0] * w[0][c] + a[r][1] * w[1][c]
                               + a[r][2] * w[2][c] + a[r][3] * w[3][c];
        }
        __syncthreads();
    }
#pragma unroll
    for (int r = 0; r < 4; ++r) {
        int row = row0 + ty * 4 + r;
        int nid = go_nid[row];
#pragma unroll
        for (int c = 0; c < 4; ++c) {
            int j = tx * 4 + c;
            out[(size_t)row * 64 + j] = acc[r][c] + lin_b[j] + go_emb[(size_t)nid * 64 + j];
        }
    }
}

// ---------------- CSR build ----------------
__global__ void count_int(const int* __restrict__ dst, int* __restrict__ cnt, int nE) {
    int e = blockIdx.x * blockDim.x + threadIdx.x;
    if (e < nE) atomicAdd(&cnt[dst[e]], 1);
}

__global__ __launch_bounds__(1024) void scan_local(const int* __restrict__ cnt,
        int* __restrict__ loc, int* __restrict__ bsum, int n) {
    __shared__ int sh[1024];
    int i = blockIdx.x * 1024 + threadIdx.x;
    int v = (i < n) ? cnt[i] : 0;
    sh[threadIdx.x] = v;
    __syncthreads();
    for (int off = 1; off < 1024; off <<= 1) {
        int t = (threadIdx.x >= off) ? sh[threadIdx.x - off] : 0;
        __syncthreads();
        sh[threadIdx.x] += t;
        __syncthreads();
    }
    if (i < n) loc[i] = sh[threadIdx.x] - v;
    if (threadIdx.x == 1023) bsum[blockIdx.x] = sh[1023];
}

__global__ __launch_bounds__(1024) void scan_bsum(int* __restrict__ bsum, int nb) {
    __shared__ int sh[1024];
    int v = (threadIdx.x < nb) ? bsum[threadIdx.x] : 0;
    sh[threadIdx.x] = v;
    __syncthreads();
    for (int off = 1; off < 1024; off <<= 1) {
        int t = (threadIdx.x >= off) ? sh[threadIdx.x - off] : 0;
        __syncthreads();
        sh[threadIdx.x] += t;
        __syncthreads();
    }
    if (threadIdx.x < nb) bsum[threadIdx.x] = sh[threadIdx.x] - v;
}

__global__ void scan_add(const int* __restrict__ loc, const int* __restrict__ bsum,
                         int* __restrict__ rowptr, int* __restrict__ cursor, int n, int total) {
    int i = blockIdx.x * blockDim.x + threadIdx.x;
    if (i < n) {
        int v = loc[i] + bsum[i >> 10];
        rowptr[i] = v;
        cursor[i] = v;
    }
    if (i == n) rowptr[n] = total;
}

__global__ void fill_csr(const int* __restrict__ src, const int* __restrict__ dst,
                         int* __restrict__ cursor, int* __restrict__ csr_src, int nE) {
    int e = blockIdx.x * blockDim.x + threadIdx.x;
    if (e >= nE) return;
    int slot = atomicAdd(&cursor[dst[e]], 1);
    csr_src[slot] = src[e];
}

// ---------------- aggregation: out[d] = mean over CSR edges of x[src] ----------
// One wave per dst row; 4 quarter-waves each handle every 4th edge; each of the
// 16 lanes in a quarter-wave loads a float4 (16 lanes x 16B = one 256B row).
// Unroll 2 -> up to 8 row-gathers (2KB) in flight per wave.
__global__ void aggregate_csr(const float* __restrict__ x, const int* __restrict__ rowptr,
                              const int* __restrict__ csr_src, float* __restrict__ out, int n) {
    int row = blockIdx.x * 4 + (threadIdx.x >> 6);   // one wave per dst row
    if (row >= n) return;
    int lane = threadIdx.x & 63;
    int qg   = lane >> 4;       // quarter-wave group 0..3 -> edge offset
    int l16  = lane & 15;       // float4 index within row
    int s = rowptr[row], e = rowptr[row + 1];
    const float4* x4 = reinterpret_cast<const float4*>(x);
    float4 a0 = make_float4(0.f, 0.f, 0.f, 0.f);
    float4 a1 = make_float4(0.f, 0.f, 0.f, 0.f);
    int i = s + qg;
    for (; i + 4 < e; i += 8) {
        int s0 = csr_src[i];
        int s1 = csr_src[i + 4];
        float4 v0 = x4[(size_t)s0 * 16 + l16];
        float4 v1 = x4[(size_t)s1 * 16 + l16];
        a0.x += v0.x; a0.y += v0.y; a0.z += v0.z; a0.w += v0.w;
        a1.x += v1.x; a1.y += v1.y; a1.z += v1.z; a1.w += v1.w;
    }
    if (i < e) {
        int s0 = csr_src[i];
        float4 v0 = x4[(size_t)s0 * 16 + l16];
        a0.x += v0.x; a0.y += v0.y; a0.z += v0.z; a0.w += v0.w;
    }
    a0.x += a1.x; a0.y += a1.y; a0.z += a1.z; a0.w += a1.w;
    // reduce across the 4 quarter-wave groups (lanes l16, l16+16, l16+32, l16+48)
    a0.x += __shfl_xor(a0.x, 16); a0.y += __shfl_xor(a0.y, 16);
    a0.z += __shfl_xor(a0.z, 16); a0.w += __shfl_xor(a0.w, 16);
    a0.x += __shfl_xor(a0.x, 32); a0.y += __shfl_xor(a0.y, 32);
    a0.z += __shfl_xor(a0.z, 32); a0.w += __shfl_xor(a0.w, 32);
    if (qg == 0) {
        float inv = (e > s) ? 1.0f / (float)(e - s) : 0.0f;
        float4 r = make_float4(a0.x * inv, a0.y * inv, a0.z * inv, a0.w * inv);
        reinterpret_cast<float4*>(out)[(size_t)row * 16 + l16] = r;
    }
}

// ---------------- node update: out = agg@Wl + bias + x@Wr, optional ReLU ----
__global__ __launch_bounds__(256) void update_nodes(
        const float* agg, const float* __restrict__ x,
        const float* __restrict__ Wl, const float* __restrict__ bias,
        const float* __restrict__ Wr, float* out, int n, int relu) {
    __shared__ float As[64][132];    // [row][k], k in [0,128) = [agg | x]
    __shared__ float Ws[128][64];    // [k][col] = [Wl ; Wr]
    int tid = threadIdx.x;
    int j = tid & 63, rg = tid >> 6;
    int tx = tid % 16, ty = tid / 16;
    int row0 = blockIdx.x * 64;
    for (int idx = tid; idx < 64 * 64; idx += 256) {
        int k = idx >> 6, c = idx & 63;
        Ws[k][c]      = Wl[idx];
        Ws[64 + k][c] = Wr[idx];
    }
    for (int rr = rg; rr < 64; rr += 4) {
        int row = row0 + rr;
        int rc = min(row, n - 1);
        As[rr][j]      = agg[(size_t)rc * 64 + j];
        As[rr][64 + j] = x[(size_t)rc * 64 + j];
    }
    __syncthreads();
    float acc[4][4] = {};
    for (int k = 0; k < 128; k += 4) {
        float a[4][4], w[4][4];
#pragma unroll
        for (int r = 0; r < 4; ++r)
            *reinterpret_cast<float4*>(a[r]) = *reinterpret_cast<const float4*>(&As[ty * 4 + r][k]);
#pragma unroll
        for (int kk = 0; kk < 4; ++kk)
            *reinterpret_cast<float4*>(w[kk]) = *reinterpret_cast<const float4*>(&Ws[k + kk][tx * 4]);
#pragma unroll
        for (int r = 0; r < 4; ++r)
#pragma unroll
            for (int c = 0; c < 4; ++c)
                acc[r][c] += a[r][0] * w[0][c] + a[r][1] * w[1][c]
                           + a[r][2] * w[2][c] + a[r][3] * w[3][c];
    }
#pragma unroll
    for (int r = 0; r < 4; ++r) {
        int row = row0 + ty * 4 + r;
        if (row >= n) continue;
#pragma unroll
        for (int c = 0; c < 4; ++c) {
            int col = tx * 4 + c;
            float v = acc[r][c] + bias[col];
            if (relu) v = fmaxf(v, 0.0f);
            out[(size_t)row * 64 + col] = v;
        }
    }
}

// ---------------- classifier: out[e] = dot(xp[ls[e]], xg[ld[e]]) ----------------
// 16 lanes per edge, float4 per lane, 4-step shfl_xor reduce within the group.
__global__ void classify(const float* __restrict__ xp, const float* __restrict__ xg,
                         const int* __restrict__ ls, const int* __restrict__ ld,
                         float* __restrict__ out, int nE) {
    int t = blockIdx.x * blockDim.x + threadIdx.x;
    int e = t >> 4;
    int l16 = t & 15;
    if (e >= nE) return;
    int s = ls[e], d = ld[e];
    float4 a = reinterpret_cast<const float4*>(xp)[(size_t)s * 16 + l16];
    float4 b = reinterpret_cast<const float4*>(xg)[(size_t)d * 16 + l16];
    float v = a.x * b.x + a.y * b.y + a.z * b.z + a.w * b.w;
    v += __shfl_xor(v, 8);
    v += __shfl_xor(v, 4);
    v += __shfl_xor(v, 2);
    v += __shfl_xor(v, 1);
    if (l16 == 0) out[e] = v;
}

extern "C" void kernel_launch(void* const* d_in, const int* in_sizes, int n_in,
                              void* d_out, int out_size, void* d_ws, size_t ws_size,
                              hipStream_t stream) {
    const float* go_x        = (const float*)d_in[0];
    const float* protein_emb = (const float*)d_in[1];
    const float* go_emb      = (const float*)d_in[2];
    const float* lin_W       = (const float*)d_in[3];
    const float* lin_b       = (const float*)d_in[4];
    const float* Wl          = (const float*)d_in[5];
    const float* bl          = (const float*)d_in[6];
    const float* Wr          = (const float*)d_in[7];
    const int* protein_nid   = (const int*)d_in[8];
    const int* go_nid        = (const int*)d_in[9];
    const int* src_pg        = (const int*)d_in[10];
    const int* dst_pg        = (const int*)d_in[11];
    const int* src_gp        = (const int*)d_in[12];
    const int* dst_gp        = (const int*)d_in[13];
    const int* label_src     = (const int*)d_in[14];
    const int* label_dst     = (const int*)d_in[15];
    float* out = (float*)d_out;

    // ---- workspace layout ----
    float* ws = (float*)d_ws;
    float* p0 = ws;
    float* p1 = p0 + (size_t)N_P * 64;
    float* g0 = p1 + (size_t)N_P * 64;
    float* g1 = g0 + (size_t)N_G * 64;
    int* ib = (int*)(g1 + (size_t)N_G * 64);
    int* rowptr_g = ib;                 ib += N_G + 1;
    int* cursor_g = ib;                 ib += N_G + 1;
    int* rowptr_p = ib;                 ib += N_P + 1;
    int* cursor_p = ib;                 ib += N_P + 1;
    int* cnt_i    = ib;                 ib += N_P;        // reused for both sides
    int* loc      = ib;                 ib += N_P;        // reused
    int* bsum     = ib;                 ib += 1024;
    int* csr_g    = ib;                 ib += NE;
    int* csr_p    = ib;                 ib += NE;

    // ---- input embeddings (independent of CSR build) ----
    gather_rows<<<(N_P * (DD / 4) + 255) / 256, 256, 0, stream>>>(protein_emb, protein_nid, p0, N_P);
    lin_go<<<N_G / 64, 256, 0, stream>>>(go_x, lin_W, lin_b, go_emb, go_nid, g0);

    // ---- build CSR for p->g edges (grouped by dst_pg, n=N_G) ----
    hipMemsetAsync(cnt_i, 0, (size_t)N_G * sizeof(int), stream);
    count_int<<<(NE + 255) / 256, 256, 0, stream>>>(dst_pg, cnt_i, NE);
    scan_local<<<(N_G + 1023) / 1024, 1024, 0, stream>>>(cnt_i, loc, bsum, N_G);
    scan_bsum<<<1, 1024, 0, stream>>>(bsum, (N_G + 1023) / 1024);
    scan_add<<<(N_G + 256) / 256, 256, 0, stream>>>(loc, bsum, rowptr_g, cursor_g, N_G, NE);
    fill_csr<<<(NE + 255) / 256, 256, 0, stream>>>(src_pg, dst_pg, cursor_g, csr_g, NE);

    // ---- build CSR for g->p edges (grouped by dst_gp, n=N_P) ----
    hipMemsetAsync(cnt_i, 0, (size_t)N_P * sizeof(int), stream);
    count_int<<<(NE + 255) / 256, 256, 0, stream>>>(dst_gp, cnt_i, NE);
    scan_local<<<(N_P + 1023) / 1024, 1024, 0, stream>>>(cnt_i, loc, bsum, N_P);
    scan_bsum<<<1, 1024, 0, stream>>>(bsum, (N_P + 1023) / 1024);
    scan_add<<<(N_P + 256) / 256, 256, 0, stream>>>(loc, bsum, rowptr_p, cursor_p, N_P, NE);
    fill_csr<<<(NE + 255) / 256, 256, 0, stream>>>(src_gp, dst_gp, cursor_p, csr_p, NE);

    // ---- layers ----
    float* xp = p0; float* xg = g0; float* sp = p1; float* sg = g1;
    for (int l = 0; l < 3; ++l) {
        aggregate_csr<<<(N_G + 3) / 4, 256, 0, stream>>>(xp, rowptr_g, csr_g, sg, N_G);
        aggregate_csr<<<(N_P + 3) / 4, 256, 0, stream>>>(xg, rowptr_p, csr_p, sp, N_P);
        int relu = (l < 2) ? 1 : 0;
        const float* wl0 = Wl + (size_t)(l * 2 + 0) * 4096;
        const float* wl1 = Wl + (size_t)(l * 2 + 1) * 4096;
        const float* wr0 = Wr + (size_t)(l * 2 + 0) * 4096;
        const float* wr1 = Wr + (size_t)(l * 2 + 1) * 4096;
        const float* b0  = bl + (size_t)(l * 2 + 0) * 64;
        const float* b1  = bl + (size_t)(l * 2 + 1) * 64;
        update_nodes<<<(N_G + 63) / 64, 256, 0, stream>>>(sg, xg, wl0, b0, wr0, sg, N_G, relu);
        update_nodes<<<(N_P + 63) / 64, 256, 0, stream>>>(sp, xp, wl1, b1, wr1, sp, N_P, relu);
        float* t;
        t = xp; xp = sp; sp = t;
        t = xg; xg = sg; sg = t;
    }
    classify<<<(E_LBL * 16 + 255) / 256, 256, 0, stream>>>(xp, xg, label_src, label_dst, out, E_LBL);
}